// Round 3
// baseline (216.107 us; speedup 1.0000x reference)
//
#include <hip/hip_runtime.h>

#define MAXP 1048576           // static pair bound (MAX_PAIRS)
#define NATOMS 8192
#define D2_CUT 0x1.8ffffep+4f  // fl(sqrt(s))<5  <=>  s < 25-2^-19

// d_ws layout (float offsets). Total usage: 49152 floats = 192 KB — strictly
// below the previous session's proven-safe ~231 KB workspace footprint.
#define W_P4     0             // float4[8192] (x,y,z,sq), 16B aligned
#define W_ROWCNT 32768         // 8192 ints
#define W_ROWOFF 40960         // 8192 ints

__device__ __forceinline__ float sq3_nc(float x, float y, float z) {
#pragma clang fp contract(off)
  float a = x * x;
  float b = y * y;
  float c = z * z;
  return (a + b) + c;
}

// mask per _pairwise_dist: sq_i + sq_j - 2*(x @ x.T); BLAS K=3 FMA chain (bit-exact, proven)
__device__ __forceinline__ float d2_gram(float xi, float yi, float zi, float sqi,
                                         float xj, float yj, float zj, float sqj) {
#pragma clang fp contract(off)
  float g = xi * xj;
  g = __builtin_fmaf(yi, yj, g);
  g = __builtin_fmaf(zi, zj, g);
  float t = sqi + sqj;
  float d2 = t - 2.0f * g;
  return d2;
}

__device__ __forceinline__ float d2_direct(float xi, float yi, float zi,
                                           float xj, float yj, float zj) {
#pragma clang fp contract(off)
  float dx = xj - xi;
  float dy = yj - yi;
  float dz = zj - zi;
  float a = dx * dx;
  float b = dy * dy;
  float c = dz * dz;
  return (a + b) + c;
}

// K0: zero the full output (padding must be exactly 0) + pack (x,y,z,sq) per atom.
// Full-chip grid so the 16.8 MB zero runs at HBM write BW.
__global__ __launch_bounds__(256) void nl_pack(const float* __restrict__ pos,
                                               float* __restrict__ out,
                                               float* __restrict__ ws) {
  const int gtid = blockIdx.x * 256 + threadIdx.x;  // 65536 threads
  float4* o4 = (float4*)out;                        // 4*MAXP floats = 1,048,576 float4
#pragma unroll
  for (int k = 0; k < 16; ++k)
    o4[k * 65536 + gtid] = make_float4(0.f, 0.f, 0.f, 0.f);
  if (gtid < NATOMS) {
    float x = pos[3 * gtid], y = pos[3 * gtid + 1], z = pos[3 * gtid + 2];
    ((float4*)(ws + W_P4))[gtid] = make_float4(x, y, z, sq3_nc(x, y, z));
  }
}

// K1: brute-force O(N^2) COUNT ONLY. One wave owns 8 consecutive rows and streams
// all 128 j-tiles; per tile one coalesced float4 load amortized over 8 rows.
// Count via ballot+popcll (SALU). Self-pair removed by clearing one ballot bit in
// the (wave-uniform) self tile. No stores except 8 ints/wave at the end.
// GRID MUST BE 256: 256 blocks x 4 waves x 8 rows = 8192 rows.
__global__ __launch_bounds__(256) void nl_count(const float* __restrict__ pos,
                                                float* __restrict__ ws) {
  const int tid = threadIdx.x;
  const int lane = tid & 63;
  const int wave = tid >> 6;
  const int rowbase = (blockIdx.x * 4 + wave) * 8;  // 8 rows/wave, all in one 64-tile

  const float4* __restrict__ p4 = (const float4*)(ws + W_P4);
  int* rowcnt = (int*)(ws + W_ROWCNT);

  float xi[8], yi[8], zi[8], sqi[8];
#pragma unroll
  for (int r = 0; r < 8; ++r) {
    int row = rowbase + r;
    xi[r] = pos[3 * row];
    yi[r] = pos[3 * row + 1];
    zi[r] = pos[3 * row + 2];
    sqi[r] = sq3_nc(xi[r], yi[r], zi[r]);
  }

  int cnt[8] = {0, 0, 0, 0, 0, 0, 0, 0};
  const int selfTile = rowbase >> 6;  // rowbase%8==0 -> all 8 rows in this tile

#pragma unroll 4
  for (int t = 0; t < 128; ++t) {
    float4 p = p4[t * 64 + lane];
#pragma unroll
    for (int r = 0; r < 8; ++r) {
      float d2 = d2_gram(xi[r], yi[r], zi[r], sqi[r], p.x, p.y, p.z, p.w);
      unsigned long long m = __ballot((d2 < D2_CUT) ? 1 : 0);
      if (t == selfTile) m &= ~(1ull << ((rowbase & 63) + r));  // drop self-pair
      cnt[r] += __popcll(m);
    }
  }
  if (lane == 0) {
#pragma unroll
    for (int r = 0; r < 8; ++r) rowcnt[rowbase + r] = cnt[r];
  }
}

// K2: exclusive scan of 8192 row counts
__global__ __launch_bounds__(1024) void nl_rowscan(float* __restrict__ ws) {
  const int* cnts = (const int*)(ws + W_ROWCNT);
  int* offs = (int*)(ws + W_ROWOFF);
  __shared__ int s[1024];
  const int tid = threadIdx.x;
  const int base = tid * 8;
  int local[8];
  int sum = 0;
#pragma unroll
  for (int k = 0; k < 8; ++k) { local[k] = sum; sum += cnts[base + k]; }
  s[tid] = sum;
  __syncthreads();
  for (int off = 1; off < 1024; off <<= 1) {
    int v = (tid >= off) ? s[tid - off] : 0;
    __syncthreads();
    s[tid] += v;
    __syncthreads();
  }
  int excl = (tid == 0) ? 0 : s[tid - 1];
#pragma unroll
  for (int k = 0; k < 8; ++k) offs[base + k] = excl + local[k];
}

// K3: re-run the brute-force scan and write hits directly to out at
// rowoff[row] + running prefix. j ascends, so output is row-major ordered —
// no sort, no intermediate j-list, no extra workspace.
// GRID MUST BE 256: 256 blocks x 4 waves x 8 rows = 8192 rows (r2 bug: was 2048).
__global__ __launch_bounds__(256) void nl_write(const float* __restrict__ pos,
                                               float* __restrict__ out,
                                               const float* __restrict__ ws) {
  const int tid = threadIdx.x;
  const int lane = tid & 63;
  const int wave = tid >> 6;
  const int rowbase = (blockIdx.x * 4 + wave) * 8;

  const float4* __restrict__ p4 = (const float4*)(ws + W_P4);
  const int* rowoff = (const int*)(ws + W_ROWOFF);

  float xi[8], yi[8], zi[8], sqi[8];
  int base[8];
#pragma unroll
  for (int r = 0; r < 8; ++r) {
    int row = rowbase + r;
    xi[r] = pos[3 * row];
    yi[r] = pos[3 * row + 1];
    zi[r] = pos[3 * row + 2];
    sqi[r] = sq3_nc(xi[r], yi[r], zi[r]);
    base[r] = rowoff[row];
  }

  int cnt[8] = {0, 0, 0, 0, 0, 0, 0, 0};
  const int selfTile = rowbase >> 6;
  const unsigned long long lmask = (1ull << lane) - 1ull;

  for (int t = 0; t < 128; ++t) {
    float4 p = p4[t * 64 + lane];
    const int j = t * 64 + lane;
#pragma unroll
    for (int r = 0; r < 8; ++r) {
      const int row = rowbase + r;
      float d2 = d2_gram(xi[r], yi[r], zi[r], sqi[r], p.x, p.y, p.z, p.w);
      bool pred = d2 < D2_CUT;
      unsigned long long m = __ballot(pred ? 1 : 0);
      if (t == selfTile) m &= ~(1ull << ((rowbase & 63) + r));  // drop self-pair
      if (pred && j != row) {
        int o = base[r] + cnt[r] + __popcll(m & lmask);
        if ((unsigned)o < MAXP) {  // unsigned: also rejects any negative index
          float ds = sqrtf(d2_direct(xi[r], yi[r], zi[r], p.x, p.y, p.z));
          ((float2*)out)[o] = make_float2((float)row, (float)j);  // interleaved pair
          out[2 * MAXP + o] = (row < j) ? 1.0f : 0.0f;            // buffer_scales
          out[3 * MAXP + o] = ds;                                 // ds
        }
      }
      cnt[r] += __popcll(m);
    }
  }
}

extern "C" void kernel_launch(void* const* d_in, const int* in_sizes, int n_in,
                              void* d_out, int out_size, void* d_ws, size_t ws_size,
                              hipStream_t stream) {
  const float* pos = (const float*)d_in[0];  // float32 [8192,3]
  float* out = (float*)d_out;                // float32 [4*MAXP]
  float* ws = (float*)d_ws;

  nl_pack<<<256, 256, 0, stream>>>(pos, out, ws);
  nl_count<<<256, 256, 0, stream>>>(pos, ws);
  nl_rowscan<<<1, 1024, 0, stream>>>(ws);
  nl_write<<<256, 256, 0, stream>>>(pos, out, ws);
}

// Round 4
// 119.014 us; speedup vs baseline: 1.8158x; 1.8158x over previous
//
#include <hip/hip_runtime.h>

#define MAXP 1048576           // static pair bound (MAX_PAIRS)
#define NATOMS 8192
#define D2_CUT 0x1.8ffffep+4f  // fl(sqrt(s))<5  <=>  s < 25-2^-19
#define CAPW 256               // LDS stage entries per wave (avg ~33 hits/wave)

// d_ws layout (float offsets). Total 224 KB <= proven-safe 231 KB.
#define W_P4     0             // float4[8192] (x,y,z,sq), 16B aligned
#define W_SCNT   32768         // u8[8192][8] per-(row,slice) counts (64 KB)
#define W_ROWOFF 49152         // int[8192] exclusive row offsets

__device__ __forceinline__ float sq3_nc(float x, float y, float z) {
#pragma clang fp contract(off)
  float a = x * x;
  float b = y * y;
  float c = z * z;
  return (a + b) + c;
}

// mask per _pairwise_dist: sq_i + sq_j - 2*(x @ x.T); BLAS K=3 FMA chain (bit-exact, proven)
__device__ __forceinline__ float d2_gram(float xi, float yi, float zi, float sqi,
                                         float xj, float yj, float zj, float sqj) {
#pragma clang fp contract(off)
  float g = xi * xj;
  g = __builtin_fmaf(yi, yj, g);
  g = __builtin_fmaf(zi, zj, g);
  float t = sqi + sqj;
  float d2 = t - 2.0f * g;
  return d2;
}

__device__ __forceinline__ float d2_direct(float xi, float yi, float zi,
                                           float xj, float yj, float zj) {
#pragma clang fp contract(off)
  float dx = xj - xi;
  float dy = yj - yi;
  float dz = zj - zi;
  float a = dx * dx;
  float b = dy * dy;
  float c = dz * dz;
  return (a + b) + c;
}

__device__ __forceinline__ int bytesum8(unsigned long long v) {
  unsigned lo = (unsigned)v, hi = (unsigned)(v >> 32);
  int s = (int)(lo & 255u) + (int)((lo >> 8) & 255u) + (int)((lo >> 16) & 255u) + (int)(lo >> 24);
  s += (int)(hi & 255u) + (int)((hi >> 8) & 255u) + (int)((hi >> 16) & 255u) + (int)(hi >> 24);
  return s;
}

// K0: zero the full output (padding must be exactly 0) + pack (x,y,z,sq) per atom.
__global__ __launch_bounds__(256) void nl_pack(const float* __restrict__ pos,
                                               float* __restrict__ out,
                                               float* __restrict__ ws) {
  const int gtid = blockIdx.x * 256 + threadIdx.x;  // 65536 threads
  float4* o4 = (float4*)out;                        // 4*MAXP floats = 1,048,576 float4
#pragma unroll
  for (int k = 0; k < 16; ++k)
    o4[k * 65536 + gtid] = make_float4(0.f, 0.f, 0.f, 0.f);
  if (gtid < NATOMS) {
    float x = pos[3 * gtid], y = pos[3 * gtid + 1], z = pos[3 * gtid + 2];
    ((float4*)(ws + W_P4))[gtid] = make_float4(x, y, z, sq3_nc(x, y, z));
  }
}

// K1: COUNT. Wave = (row-group of 8, j-slice of 16 tiles). 8192 waves -> 8/SIMD.
// Per-lane predicate accumulate (no ballot in the hot loop), one shuffle-reduce
// per wave at the end. Self-pair: uniform -1 in the self slice (self always hits).
// GRID: 2048 blocks x 256.
__global__ __launch_bounds__(256, 8) void nl_count(const float* __restrict__ pos,
                                                   float* __restrict__ ws) {
  const int lane = threadIdx.x & 63;
  const int wave = threadIdx.x >> 6;
  const int w = blockIdx.x * 4 + wave;  // 0..8191
  const int g = w >> 3;                 // row group 0..1023
  const int s = w & 7;                  // slice 0..7
  const int rowbase = g * 8;
  const int t0 = s * 16;

  const float4* __restrict__ p4 = (const float4*)(ws + W_P4);
  unsigned char* scnt = (unsigned char*)(ws + W_SCNT);

  float xi[8], yi[8], zi[8], sqi[8];
#pragma unroll
  for (int r = 0; r < 8; ++r) {
    int row = rowbase + r;
    xi[r] = pos[3 * row];
    yi[r] = pos[3 * row + 1];
    zi[r] = pos[3 * row + 2];
    sqi[r] = sq3_nc(xi[r], yi[r], zi[r]);
  }

  int cnt[8] = {0, 0, 0, 0, 0, 0, 0, 0};
#pragma unroll 2
  for (int tt = 0; tt < 16; ++tt) {
    float4 p = p4[(t0 + tt) * 64 + lane];
#pragma unroll
    for (int r = 0; r < 8; ++r) {
      float d2 = d2_gram(xi[r], yi[r], zi[r], sqi[r], p.x, p.y, p.z, p.w);
      cnt[r] += (d2 < D2_CUT) ? 1 : 0;
    }
  }
#pragma unroll
  for (int r = 0; r < 8; ++r)
    for (int off = 32; off > 0; off >>= 1) cnt[r] += __shfl_down(cnt[r], off, 64);

  if (lane == 0) {
    const int selfSlice = (rowbase >> 6) >> 4;  // all 8 rows share one self tile
#pragma unroll
    for (int r = 0; r < 8; ++r)
      scnt[(rowbase + r) * 8 + s] = (unsigned char)(cnt[r] - ((s == selfSlice) ? 1 : 0));
  }
}

// K2: row totals (u64 byte-sum) + exclusive scan over 8192 rows.
__global__ __launch_bounds__(1024) void nl_rowscan(float* __restrict__ ws) {
  const unsigned long long* sc = (const unsigned long long*)(ws + W_SCNT);
  int* offs = (int*)(ws + W_ROWOFF);
  __shared__ int s[1024];
  const int tid = threadIdx.x;
  const int base = tid * 8;
  int local[8];
  int sum = 0;
#pragma unroll
  for (int k = 0; k < 8; ++k) { local[k] = sum; sum += bytesum8(sc[base + k]); }
  s[tid] = sum;
  __syncthreads();
  for (int off = 1; off < 1024; off <<= 1) {
    int v = (tid >= off) ? s[tid - off] : 0;
    __syncthreads();
    s[tid] += v;
    __syncthreads();
  }
  int excl = (tid == 0) ? 0 : s[tid - 1];
#pragma unroll
  for (int k = 0; k < 8; ++k) offs[base + k] = excl + local[k];
}

// K3: WRITE. Wave = (row-group of 4, j-slice of 16 tiles). 16384 waves.
// Phase 1: re-scan, stage (o, j|r<<16) int2 into wave-private LDS (cheap guarded
// block; o from the same mbcnt as the stage slot). Phase 2: replay staged hits
// with all 64 lanes: gather p4[row]/p4[j], bit-exact d2_direct+sqrtf, 3 stores.
// Output order = reference row-major: rows ascend, slices ascend in j, j ascends.
// GRID: 4096 blocks x 256.
__global__ __launch_bounds__(256, 8) void nl_write(const float* __restrict__ pos,
                                                   float* __restrict__ out,
                                                   const float* __restrict__ ws) {
  __shared__ int2 stage[4][CAPW];
  const int lane = threadIdx.x & 63;
  const int wave = threadIdx.x >> 6;
  const int w = blockIdx.x * 4 + wave;  // 0..16383
  const int g = w >> 3;                 // row group 0..2047
  const int s = w & 7;                  // slice 0..7
  const int rowbase = g * 4;
  const int t0 = s * 16;

  const float4* __restrict__ p4 = (const float4*)(ws + W_P4);
  const unsigned long long* sc = (const unsigned long long*)(ws + W_SCNT);
  const int* rowoff = (const int*)(ws + W_ROWOFF);

  float xi[4], yi[4], zi[4], sqi[4];
  int br[4];  // running output offset for row r = rowoff + earlier-slice hits + hits so far
  const unsigned long long smask = (1ull << (8 * s)) - 1ull;  // s==0 -> 0
#pragma unroll
  for (int r = 0; r < 4; ++r) {
    int row = rowbase + r;
    xi[r] = pos[3 * row];
    yi[r] = pos[3 * row + 1];
    zi[r] = pos[3 * row + 2];
    sqi[r] = sq3_nc(xi[r], yi[r], zi[r]);
    br[r] = rowoff[row] + bytesum8(sc[row] & smask);
  }

  int wcnt = 0;
  const int selfTile = rowbase >> 6;  // all 4 rows share one self tile
  const unsigned long long lmask = (1ull << lane) - 1ull;

  for (int tt = 0; tt < 16; ++tt) {
    const int t = t0 + tt;
    float4 p = p4[t * 64 + lane];
    const int j = t * 64 + lane;
#pragma unroll
    for (int r = 0; r < 4; ++r) {
      const int row = rowbase + r;
      float d2 = d2_gram(xi[r], yi[r], zi[r], sqi[r], p.x, p.y, p.z, p.w);
      bool pred = d2 < D2_CUT;
      unsigned long long m = __ballot(pred ? 1 : 0);
      if (t == selfTile) m &= ~(1ull << ((rowbase & 63) + r));  // drop self-pair
      if (pred && j != row) {
        int mb = __popcll(m & lmask);
        int widx = wcnt + mb;
        if (widx < CAPW) stage[wave][widx] = make_int2(br[r] + mb, j | (r << 16));
      }
      int pc = __popcll(m);
      br[r] += pc;
      wcnt += pc;
    }
  }
  if (wcnt > CAPW) wcnt = CAPW;

  // phase 2: wave-private LDS, no barrier needed (compiler inserts lgkmcnt waits)
  for (int i = lane; i < wcnt; i += 64) {
    int2 e = stage[wave][i];
    int o = e.x;
    int j = e.y & 0xFFFF;
    int row = rowbase + (e.y >> 16);
    float4 pi = p4[row];  // gather (L1-hit); avoids runtime-indexed register array
    float4 pj = p4[j];
    float ds = sqrtf(d2_direct(pi.x, pi.y, pi.z, pj.x, pj.y, pj.z));
    if ((unsigned)o < MAXP) {
      ((float2*)out)[o] = make_float2((float)row, (float)j);  // interleaved pair
      out[2 * MAXP + o] = (row < j) ? 1.0f : 0.0f;            // buffer_scales
      out[3 * MAXP + o] = ds;                                 // ds
    }
  }
}

extern "C" void kernel_launch(void* const* d_in, const int* in_sizes, int n_in,
                              void* d_out, int out_size, void* d_ws, size_t ws_size,
                              hipStream_t stream) {
  const float* pos = (const float*)d_in[0];  // float32 [8192,3]
  float* out = (float*)d_out;                // float32 [4*MAXP]
  float* ws = (float*)d_ws;

  nl_pack<<<256, 256, 0, stream>>>(pos, out, ws);
  nl_count<<<2048, 256, 0, stream>>>(pos, ws);
  nl_rowscan<<<1, 1024, 0, stream>>>(ws);
  nl_write<<<4096, 256, 0, stream>>>(pos, out, ws);
}

// Round 5
// 96.036 us; speedup vs baseline: 2.2503x; 1.2393x over previous
//
#include <hip/hip_runtime.h>

#define MAXP 1048576           // static pair bound (MAX_PAIRS)
#define NATOMS 8192
#define D2_CUT 0x1.8ffffep+4f  // fl(sqrt(s))<5  <=>  s < 25-2^-19
#define CINV 0.175f            // 7/40: 7^3=343 cells, width 5.714 > 5.0004 (conservative)
#define CAP 192                // max hits/row (avg ~67)

// d_ws layout (float offsets). Total 54784 floats = 214 KB < proven-safe 226 KB.
#define W_SORTPOS 0            // float4[8192] cell-sorted (x,y,z,sq)
#define W_SORTID  32768        // u16[8192] sorted slot -> original atom id (4096 floats)
#define W_ROWCNT  36864        // int[8192]
#define W_ROWOFF  45056        // int[8192]
#define W_CELLOFF 53248        // int[344], padded to 512
#define W_CELLCNT 53760        // int[344], padded to 512
#define W_CELLCUR 54272        // int[344], padded to 512

__device__ __forceinline__ float sq3_nc(float x, float y, float z) {
#pragma clang fp contract(off)
  float a = x * x;
  float b = y * y;
  float c = z * z;
  return (a + b) + c;
}

// mask per _pairwise_dist: sq_i + sq_j - 2*(x @ x.T); BLAS K=3 FMA chain (bit-exact, proven)
__device__ __forceinline__ float d2_gram(float xi, float yi, float zi, float sqi,
                                         float xj, float yj, float zj, float sqj) {
#pragma clang fp contract(off)
  float g = xi * xj;
  g = __builtin_fmaf(yi, yj, g);
  g = __builtin_fmaf(zi, zj, g);
  float t = sqi + sqj;
  float d2 = t - 2.0f * g;
  return d2;
}

__device__ __forceinline__ float d2_direct(float xi, float yi, float zi,
                                           float xj, float yj, float zj) {
#pragma clang fp contract(off)
  float dx = xj - xi;
  float dy = yj - yi;
  float dz = zj - zi;
  float a = dx * dx;
  float b = dy * dy;
  float c = dz * dz;
  return (a + b) + c;
}

__device__ __forceinline__ int cellco(float v) {
  int c = (int)(v * CINV);
  return c < 0 ? 0 : (c > 6 ? 6 : c);
}

// K0: zero 16.8 MB output (padding must be exactly 0) + zero cell counters.
__global__ __launch_bounds__(256) void nl_pack(float* __restrict__ out,
                                               float* __restrict__ ws) {
  const int gtid = blockIdx.x * 256 + threadIdx.x;  // 65536 threads
  float4* o4 = (float4*)out;                        // 4*MAXP floats = 1,048,576 float4
#pragma unroll
  for (int k = 0; k < 16; ++k)
    o4[k * 65536 + gtid] = make_float4(0.f, 0.f, 0.f, 0.f);
  if (gtid < 512) ((int*)(ws + W_CELLCNT))[gtid] = 0;
}

// K1: per-atom cell histogram (8192 global atomics over 343 counters).
__global__ __launch_bounds__(256) void nl_cellcount(const float* __restrict__ pos,
                                                    float* __restrict__ ws) {
  const int a = blockIdx.x * 256 + threadIdx.x;  // 8192 threads
  float x = pos[3 * a], y = pos[3 * a + 1], z = pos[3 * a + 2];
  int cl = cellco(x) + 7 * cellco(y) + 49 * cellco(z);
  atomicAdd(&((int*)(ws + W_CELLCNT))[cl], 1);
}

// K2: tiny 343-scan -> celloff[344]; zero cellcur. One block (trivial work).
__global__ __launch_bounds__(512) void nl_cellscan(float* __restrict__ ws) {
  const int* cellcnt = (const int*)(ws + W_CELLCNT);
  int* celloff = (int*)(ws + W_CELLOFF);
  int* cellcur = (int*)(ws + W_CELLCUR);
  __shared__ int s[512];
  const int tid = threadIdx.x;
  s[tid] = (tid < 343) ? cellcnt[tid] : 0;
  __syncthreads();
  for (int off = 1; off < 512; off <<= 1) {
    int v = (tid >= off) ? s[tid - off] : 0;
    __syncthreads();
    s[tid] += v;
    __syncthreads();
  }
  if (tid < 344) celloff[tid] = (tid == 0) ? 0 : s[tid - 1];
  cellcur[tid] = 0;
}

// K3: scatter atoms into cell-sorted storage (within-cell order arbitrary —
// downstream is order-independent by construction).
__global__ __launch_bounds__(256) void nl_scatter(const float* __restrict__ pos,
                                                  float* __restrict__ ws) {
  const int a = blockIdx.x * 256 + threadIdx.x;  // 8192 threads
  float x = pos[3 * a], y = pos[3 * a + 1], z = pos[3 * a + 2];
  int cl = cellco(x) + 7 * cellco(y) + 49 * cellco(z);
  int slot = ((const int*)(ws + W_CELLOFF))[cl] +
             atomicAdd(&((int*)(ws + W_CELLCUR))[cl], 1);
  ((float4*)(ws + W_SORTPOS))[slot] = make_float4(x, y, z, sq3_nc(x, y, z));
  ((unsigned short*)(ws + W_SORTID))[slot] = (unsigned short)a;
}

// K4: COUNT. One wave per row, 27-cell (9 x-strip) candidate scan, per-lane
// predicate accumulate, one shuffle-reduce. Self always predicates true
// (d2_self = 2*(sq - g_fma) ~ ±eps < cut) -> subtract 1 unconditionally.
// GRID 2048 x 256 -> 8192 waves -> 8/SIMD.
__global__ __launch_bounds__(256, 4) void nl_count(const float* __restrict__ pos,
                                                   float* __restrict__ ws) {
  const int lane = threadIdx.x & 63;
  const int wave = threadIdx.x >> 6;
  const int row = blockIdx.x * 4 + wave;

  const float4* __restrict__ sp4 = (const float4*)(ws + W_SORTPOS);
  const int* __restrict__ celloff = (const int*)(ws + W_CELLOFF);
  int* rowcnt = (int*)(ws + W_ROWCNT);

  const float xi = pos[3 * row], yi = pos[3 * row + 1], zi = pos[3 * row + 2];
  const float sqi = sq3_nc(xi, yi, zi);
  int cx = cellco(xi), cy = cellco(yi), cz = cellco(zi);
  int x0 = max(cx - 1, 0), x1 = min(cx + 1, 6);
  int y0 = max(cy - 1, 0), y1 = min(cy + 1, 6);
  int z0 = max(cz - 1, 0), z1 = min(cz + 1, 6);

  int cnt = 0;
  for (int icz = z0; icz <= z1; ++icz)
    for (int icy = y0; icy <= y1; ++icy) {
      int cb = 7 * icy + 49 * icz;
      int st = celloff[cb + x0];
      int en = celloff[cb + x1 + 1];
      for (int bb = st; bb < en; bb += 64) {
        int t = bb + lane;
        bool v = t < en;
        int t2 = v ? t : (en - 1);  // clamp: always a valid slot; pred killed by v
        float4 p = sp4[t2];
        float d2 = d2_gram(xi, yi, zi, sqi, p.x, p.y, p.z, p.w);
        cnt += (v && d2 < D2_CUT) ? 1 : 0;
      }
    }
  for (int off = 32; off > 0; off >>= 1) cnt += __shfl_down(cnt, off, 64);
  if (lane == 0) rowcnt[row] = cnt - 1;  // remove self-pair
}

// K5: exclusive scan of 8192 row counts.
__global__ __launch_bounds__(1024) void nl_rowscan(float* __restrict__ ws) {
  const int* cnts = (const int*)(ws + W_ROWCNT);
  int* offs = (int*)(ws + W_ROWOFF);
  __shared__ int s[1024];
  const int tid = threadIdx.x;
  const int base = tid * 8;
  int local[8];
  int sum = 0;
#pragma unroll
  for (int k = 0; k < 8; ++k) { local[k] = sum; sum += cnts[base + k]; }
  s[tid] = sum;
  __syncthreads();
  for (int off = 1; off < 1024; off <<= 1) {
    int v = (tid >= off) ? s[tid - off] : 0;
    __syncthreads();
    s[tid] += v;
    __syncthreads();
  }
  int excl = (tid == 0) ? 0 : s[tid - 1];
#pragma unroll
  for (int k = 0; k < 8; ++k) offs[base + k] = excl + local[k];
}

// K6: WRITE. One wave per row. Cell scan marks hits by ORIGINAL j into a
// per-row 8192-bit LDS bitmap (order-independent), clear self bit, then extract
// set bits word-ascending (= reference j order) via popcount prefix into a
// compact LDS j-list; phase 2 computes ds (bit-exact d2_direct+sqrtf on raw
// pos) and writes pairs/scales/ds densely. No sort anywhere.
__global__ __launch_bounds__(256, 4) void nl_write(const float* __restrict__ pos,
                                                   float* __restrict__ out,
                                                   const float* __restrict__ ws) {
  __shared__ unsigned int bmap[4][256];     // 8192 bits per wave
  __shared__ unsigned short stj[4][CAP];    // j-list in ascending order
  const int lane = threadIdx.x & 63;
  const int wave = threadIdx.x >> 6;
  const int row = blockIdx.x * 4 + wave;

  const float4* __restrict__ sp4 = (const float4*)(ws + W_SORTPOS);
  const unsigned short* __restrict__ sid = (const unsigned short*)(ws + W_SORTID);
  const int* __restrict__ celloff = (const int*)(ws + W_CELLOFF);
  const int* __restrict__ rowoff = (const int*)(ws + W_ROWOFF);

#pragma unroll
  for (int q = 0; q < 4; ++q) bmap[wave][lane + 64 * q] = 0u;  // wave-private, in-order

  const float xi = pos[3 * row], yi = pos[3 * row + 1], zi = pos[3 * row + 2];
  const float sqi = sq3_nc(xi, yi, zi);
  int cx = cellco(xi), cy = cellco(yi), cz = cellco(zi);
  int x0 = max(cx - 1, 0), x1 = min(cx + 1, 6);
  int y0 = max(cy - 1, 0), y1 = min(cy + 1, 6);
  int z0 = max(cz - 1, 0), z1 = min(cz + 1, 6);

  for (int icz = z0; icz <= z1; ++icz)
    for (int icy = y0; icy <= y1; ++icy) {
      int cb = 7 * icy + 49 * icz;
      int st = celloff[cb + x0];
      int en = celloff[cb + x1 + 1];
      for (int bb = st; bb < en; bb += 64) {
        int t = bb + lane;
        bool v = t < en;
        int t2 = v ? t : (en - 1);  // identical clamp as nl_count -> identical preds
        float4 p = sp4[t2];
        int jd = sid[t2];
        float d2 = d2_gram(xi, yi, zi, sqi, p.x, p.y, p.z, p.w);
        if (v && d2 < D2_CUT)
          atomicOr(&bmap[wave][jd >> 5], 1u << (jd & 31));
      }
    }
  if (lane == 0)  // self always marked (d2_self ~ ±eps < cut); clear it
    atomicAnd(&bmap[wave][row >> 5], ~(1u << (row & 31)));

  // extract in j order: 4 segments of 64 words; per-word popcount prefix
  int ktot = 0;
#pragma unroll
  for (int seg = 0; seg < 4; ++seg) {
    int w = seg * 64 + lane;
    unsigned bits = bmap[wave][w];
    int pc = __popc(bits);
    int incl = pc;
    for (int d = 1; d < 64; d <<= 1) {
      int u = __shfl_up(incl, d, 64);
      if (lane >= d) incl += u;
    }
    int base = ktot + incl - pc;
    while (bits) {
      int b = __builtin_ctz(bits);
      bits &= bits - 1;
      if (base < CAP) stj[wave][base] = (unsigned short)(w * 32 + b);
      ++base;
    }
    ktot += __shfl(incl, 63, 64);
  }

  int k = ktot > CAP ? CAP : ktot;
  int ro = rowoff[row];
  for (int s = lane; s < k; s += 64) {
    int j = stj[wave][s];
    int o = ro + s;
    if ((unsigned)o < MAXP) {
      float xj = pos[3 * j], yj = pos[3 * j + 1], zj = pos[3 * j + 2];
      float ds = sqrtf(d2_direct(xi, yi, zi, xj, yj, zj));
      ((float2*)out)[o] = make_float2((float)row, (float)j);  // interleaved pair
      out[2 * MAXP + o] = (row < j) ? 1.0f : 0.0f;            // buffer_scales
      out[3 * MAXP + o] = ds;                                 // ds
    }
  }
}

extern "C" void kernel_launch(void* const* d_in, const int* in_sizes, int n_in,
                              void* d_out, int out_size, void* d_ws, size_t ws_size,
                              hipStream_t stream) {
  const float* pos = (const float*)d_in[0];  // float32 [8192,3]
  float* out = (float*)d_out;                // float32 [4*MAXP]
  float* ws = (float*)d_ws;

  nl_pack<<<256, 256, 0, stream>>>(out, ws);
  nl_cellcount<<<32, 256, 0, stream>>>(pos, ws);
  nl_cellscan<<<1, 512, 0, stream>>>(ws);
  nl_scatter<<<32, 256, 0, stream>>>(pos, ws);
  nl_count<<<2048, 256, 0, stream>>>(pos, ws);
  nl_rowscan<<<1, 1024, 0, stream>>>(ws);
  nl_write<<<2048, 256, 0, stream>>>(pos, out, ws);
}